// Round 2
// baseline (778.293 us; speedup 1.0000x reference)
//
#include <hip/hip_runtime.h>
#include <math.h>

#define SIGMA 0.05f

// ---------------------------------------------------------------------------
// Fused policy MLP + softmax.
// grid = 256 blocks x 1024 threads, 4 batch rows per block.
//   phase 1: h1 = tanh(obs@W1+b1)   (1024 outputs = 1/thread, h1 -> LDS)
//   phase 2: h2 = tanh(h1@W2+b2)    (same)
//   phase 3: logits col=tid, 4 rows in registers; W3 read coalesced, L2-served
//   phase 4: per-row softmax via 64-lane butterflies + 16-wave LDS combine
// Also zeroes the argmax accumulator (stream-ordered before argmax kernel).
// ---------------------------------------------------------------------------
__global__ __launch_bounds__(1024) void mlp_kernel(
    const float* __restrict__ obs,
    const float* __restrict__ W1, const float* __restrict__ b1,
    const float* __restrict__ W2, const float* __restrict__ b2,
    const float* __restrict__ W3, const float* __restrict__ b3,
    float* __restrict__ probs, int* acc_zero)
{
    __shared__ float sobs[4 * 256];
    __shared__ float sh1[4 * 256];
    __shared__ float sh2[4 * 256];
    __shared__ float red[4][17];          // [row][wave] partials, +1 pad
    const int tid = threadIdx.x;
    const int r = tid >> 8, j = tid & 255;
    const int b0 = blockIdx.x * 4;
    const int lane = tid & 63, wave = tid >> 6;

    sobs[tid] = obs[(b0 + r) * 256 + j];
    if (blockIdx.x == 0 && tid == 0) *acc_zero = 0;
    __syncthreads();

    float a = b1[j];
#pragma unroll 8
    for (int k = 0; k < 256; ++k)
        a = fmaf(sobs[r * 256 + k], W1[k * 256 + j], a);   // LDS read broadcast
    sh1[tid] = tanhf(a);
    __syncthreads();

    a = b2[j];
#pragma unroll 8
    for (int k = 0; k < 256; ++k)
        a = fmaf(sh1[r * 256 + k], W2[k * 256 + j], a);
    sh2[tid] = tanhf(a);
    __syncthreads();

    // logits: thread owns column col=tid for all 4 rows
    const int col = tid;
    float acc4[4];
    const float bb = b3[col];
    acc4[0] = acc4[1] = acc4[2] = acc4[3] = bb;
#pragma unroll 4
    for (int k = 0; k < 256; ++k) {
        const float w = W3[k * 1024 + col];
        acc4[0] = fmaf(sh2[0 * 256 + k], w, acc4[0]);
        acc4[1] = fmaf(sh2[1 * 256 + k], w, acc4[1]);
        acc4[2] = fmaf(sh2[2 * 256 + k], w, acc4[2]);
        acc4[3] = fmaf(sh2[3 * 256 + k], w, acc4[3]);
    }

    // softmax over the 1024 columns of each row
    float M[4];
#pragma unroll
    for (int rr = 0; rr < 4; ++rr) {
        float m = acc4[rr];
#pragma unroll
        for (int off = 1; off < 64; off <<= 1) m = fmaxf(m, __shfl_xor(m, off));
        if (lane == 0) red[rr][wave] = m;
    }
    __syncthreads();
#pragma unroll
    for (int rr = 0; rr < 4; ++rr) {
        float m = red[rr][0];
#pragma unroll
        for (int wv = 1; wv < 16; ++wv) m = fmaxf(m, red[rr][wv]);
        M[rr] = m;
    }
    __syncthreads();                      // before red reuse
#pragma unroll
    for (int rr = 0; rr < 4; ++rr) {
        float e = expf(acc4[rr] - M[rr]);
        acc4[rr] = e;
#pragma unroll
        for (int off = 1; off < 64; off <<= 1) e += __shfl_xor(e, off);
        if (lane == 0) red[rr][wave] = e;
    }
    __syncthreads();
#pragma unroll
    for (int rr = 0; rr < 4; ++rr) {
        float s = 0.f;
#pragma unroll
        for (int wv = 0; wv < 16; ++wv) s += red[rr][wv];
        probs[(size_t)(b0 + rr) * 1024 + col] = acc4[rr] / s;
    }
}

// ---------------------------------------------------------------------------
// argmax scan: for each (b,n) find argmax_d(probs[b,d] + SIGMA*noise[b,n,d]),
// accumulate exact integer index sum. 512 MiB coalesced noise read = the
// HBM-bound floor of the whole problem. probs fragments hoisted to registers;
// 2 n's per wave-iteration for load/butterfly ILP.
// ---------------------------------------------------------------------------
#define NSPLIT 4

__device__ __forceinline__ void scan16(
    const float4 n0, const float4 n1, const float4 n2, const float4 n3,
    const float4 p0, const float4 p1, const float4 p2, const float4 p3,
    int lane, float& best, int& bidx)
{
    best = -1e30f; bidx = 0;
    // strict > keeps the lowest d on ties (in-lane d visited ascending)
#define CHK(val, d) { float _v = (val); if (_v > best) { best = _v; bidx = (d); } }
    int d0 = lane * 4;
    CHK(fmaf(n0.x, SIGMA, p0.x), d0 + 0); CHK(fmaf(n0.y, SIGMA, p0.y), d0 + 1);
    CHK(fmaf(n0.z, SIGMA, p0.z), d0 + 2); CHK(fmaf(n0.w, SIGMA, p0.w), d0 + 3);
    d0 = (lane + 64) * 4;
    CHK(fmaf(n1.x, SIGMA, p1.x), d0 + 0); CHK(fmaf(n1.y, SIGMA, p1.y), d0 + 1);
    CHK(fmaf(n1.z, SIGMA, p1.z), d0 + 2); CHK(fmaf(n1.w, SIGMA, p1.w), d0 + 3);
    d0 = (lane + 128) * 4;
    CHK(fmaf(n2.x, SIGMA, p2.x), d0 + 0); CHK(fmaf(n2.y, SIGMA, p2.y), d0 + 1);
    CHK(fmaf(n2.z, SIGMA, p2.z), d0 + 2); CHK(fmaf(n2.w, SIGMA, p2.w), d0 + 3);
    d0 = (lane + 192) * 4;
    CHK(fmaf(n3.x, SIGMA, p3.x), d0 + 0); CHK(fmaf(n3.y, SIGMA, p3.y), d0 + 1);
    CHK(fmaf(n3.z, SIGMA, p3.z), d0 + 2); CHK(fmaf(n3.w, SIGMA, p3.w), d0 + 3);
#undef CHK
}

__device__ __forceinline__ int wave_argmax(float best, int bidx)
{
    // 64-lane butterfly: max value, ties -> lowest index
#pragma unroll
    for (int off = 1; off < 64; off <<= 1) {
        const float ov = __shfl_xor(best, off);
        const int   oi = __shfl_xor(bidx, off);
        if (ov > best || (ov == best && oi < bidx)) { best = ov; bidx = oi; }
    }
    return bidx;
}

__global__ __launch_bounds__(256) void argmax_kernel(
    const float* __restrict__ probs, const float* __restrict__ noise,
    int* __restrict__ acc)
{
    __shared__ float ps[1024];
    __shared__ int wsum[4];
    const int b = blockIdx.x / NSPLIT;
    const int part = blockIdx.x % NSPLIT;
    const int tid = threadIdx.x;
    const int lane = tid & 63, wave = tid >> 6;

    for (int i = tid; i < 1024; i += 256)
        ps[i] = probs[(size_t)b * 1024 + i];
    __syncthreads();

    // loop-invariant probs fragments -> registers
    const float4 p0 = *(const float4*)(ps + (lane       ) * 4);
    const float4 p1 = *(const float4*)(ps + (lane +  64) * 4);
    const float4 p2 = *(const float4*)(ps + (lane + 128) * 4);
    const float4 p3 = *(const float4*)(ps + (lane + 192) * 4);

    const int nbase = part * 32 + wave * 8;   // 8 contiguous n per wave
    int mysum = 0;
    for (int i = 0; i < 8; i += 2) {
        const float* __restrict__ npa = noise + ((size_t)b * 128 + nbase + i    ) * 1024;
        const float* __restrict__ npb = noise + ((size_t)b * 128 + nbase + i + 1) * 1024;

        const float4 a0 = *(const float4*)(npa + (size_t)(lane       ) * 4);
        const float4 a1 = *(const float4*)(npa + (size_t)(lane +  64) * 4);
        const float4 a2 = *(const float4*)(npa + (size_t)(lane + 128) * 4);
        const float4 a3 = *(const float4*)(npa + (size_t)(lane + 192) * 4);
        const float4 c0 = *(const float4*)(npb + (size_t)(lane       ) * 4);
        const float4 c1 = *(const float4*)(npb + (size_t)(lane +  64) * 4);
        const float4 c2 = *(const float4*)(npb + (size_t)(lane + 128) * 4);
        const float4 c3 = *(const float4*)(npb + (size_t)(lane + 192) * 4);

        float bestA, bestB; int idxA, idxB;
        scan16(a0, a1, a2, a3, p0, p1, p2, p3, lane, bestA, idxA);
        scan16(c0, c1, c2, c3, p0, p1, p2, p3, lane, bestB, idxB);
        mysum += wave_argmax(bestA, idxA);
        mysum += wave_argmax(bestB, idxB);
    }
    if (lane == 0) wsum[wave] = mysum;
    __syncthreads();
    if (tid == 0)
        atomicAdd(acc, wsum[0] + wsum[1] + wsum[2] + wsum[3]);
}

// ---------------------------------------------------------------------------
// value head: Q[b] = tanh([obs[b,:], c] @ Wv1 + bv1) @ Wv2 + bv2,
// c = (float)acc / 128. One block per b, thread j computes hidden unit j.
// ---------------------------------------------------------------------------
__global__ __launch_bounds__(256) void value_kernel(
    const float* __restrict__ obs, const float* __restrict__ Wv1,
    const float* __restrict__ bv1, const float* __restrict__ Wv2,
    const float* __restrict__ bv2, const int* __restrict__ acc,
    float* __restrict__ Q)
{
    __shared__ float s[256];
    __shared__ float red[4];
    const int b = blockIdx.x, j = threadIdx.x;
    const int lane = j & 63, wave = j >> 6;
    s[j] = obs[b * 256 + j];
    __syncthreads();
    const float c = (float)(*acc) * (1.0f / 128.0f);
    float a = bv1[j] + c * Wv1[256 * 256 + j];   // last row of Wv1 (k = OBS)
#pragma unroll 8
    for (int k = 0; k < 256; ++k)
        a = fmaf(s[k], Wv1[k * 256 + j], a);
    float v = tanhf(a) * Wv2[j];
#pragma unroll
    for (int off = 1; off < 64; off <<= 1) v += __shfl_xor(v, off);
    if (lane == 0) red[wave] = v;
    __syncthreads();
    if (j == 0) Q[b] = red[0] + red[1] + red[2] + red[3] + bv2[0];
}

// ---------------------------------------------------------------------------
extern "C" void kernel_launch(void* const* d_in, const int* in_sizes, int n_in,
                              void* d_out, int out_size, void* d_ws, size_t ws_size,
                              hipStream_t stream)
{
    const float* obs   = (const float*)d_in[0];
    const float* noise = (const float*)d_in[1];
    const float* W1    = (const float*)d_in[2];
    const float* b1    = (const float*)d_in[3];
    const float* W2    = (const float*)d_in[4];
    const float* b2    = (const float*)d_in[5];
    const float* W3    = (const float*)d_in[6];
    const float* b3    = (const float*)d_in[7];
    const float* Wv1   = (const float*)d_in[8];
    const float* bv1   = (const float*)d_in[9];
    const float* Wv2   = (const float*)d_in[10];
    const float* bv2   = (const float*)d_in[11];
    float* Q = (float*)d_out;

    // workspace layout (floats): probs[1M], then acc (1 int)
    float* probs = (float*)d_ws;
    int*   acc   = (int*)(probs + 1024 * 1024);

    mlp_kernel<<<256, 1024, 0, stream>>>(obs, W1, b1, W2, b2, W3, b3, probs, acc);
    argmax_kernel<<<1024 * NSPLIT, 256, 0, stream>>>(probs, noise, acc);
    value_kernel<<<1024, 256, 0, stream>>>(obs, Wv1, bv1, Wv2, bv2, acc, Q);
}